// Round 3
// baseline (9793.746 us; speedup 1.0000x reference)
//
#include <hip/hip_runtime.h>
#include <hip/hip_bf16.h>

// GNNRecommender: LSTM(20 steps) + content linear + 2x bipartite SAGE + classifier.
// Round 2: dtype-agnostic (runtime fp32-vs-bf16 probe), pure-VALU compute,
// fp32 internals. Correctness first; MFMA comes back once green.

typedef __bf16 bf16;

#define N_NODES 32768
#define NMASK 32767
#define T_STEPS 20
#define EMBD 64
#define HD 128
#define G4 512   // 4*H gate width

__device__ __forceinline__ float sigf(float x) { return 1.f / (1.f + __expf(-x)); }

// dual-dtype scalar load: isbf ? bf16[i] : float[i]
__device__ __forceinline__ float ldf(const void* p, size_t i, int isbf) {
  return isbf ? (float)((const bf16*)p)[i] : ((const float*)p)[i];
}

// ---------------- dtype probe: 1 = bf16, 0 = fp32 ----------------
__global__ void k_detect(const unsigned* __restrict__ x, int* __restrict__ flag)
{
  if (threadIdx.x == 0 && blockIdx.x == 0) {
    int cnt = 0;
    for (int i = 0; i < 256; ++i) {
      const unsigned w = x[i];
      const unsigned e0 = (w >> 7) & 0xffu;          // exp field of low bf16 half
      const unsigned e1 = (w >> 23) & 0xffu;         // exp field of high bf16 half
      const bool ok0 = (e0 >= 90u && e0 <= 141u) || ((w & 0x7fffu) == 0u);
      const bool ok1 = (e1 >= 90u && e1 <= 141u) || (((w >> 16) & 0x7fffu) == 0u);
      if (ok0 && ok1) ++cnt;
    }
    *flag = (cnt >= 200) ? 1 : 0;
  }
}

// ---------------- zero-fill (graph-capture-safe) ----------------
__global__ __launch_bounds__(256) void k_zero(float4* __restrict__ p, int n4)
{
  const int i = blockIdx.x * 256 + threadIdx.x;
  if (i < n4) p[i] = float4{0.f, 0.f, 0.f, 0.f};
}

// ---------------- LSTM: one fused step (VALU GEMM + cell update) ----------------
// Block: 256 threads, 32 nodes, all 512 gate columns (thread owns cols tid, tid+256).
// smem aliasing: [xl 32x64 | hl 32x128] (24 KB) -> overwritten by gates 32x512 (64 KB).
__global__ __launch_bounds__(256) void k_lstm_step(
    const void* __restrict__ x_user, const void* __restrict__ W_ih,
    const void* __restrict__ W_hh, const void* __restrict__ b_ih,
    const void* __restrict__ b_hh,
    float* __restrict__ h, float* __restrict__ cstate,
    const int* __restrict__ flagp, int t)
{
  __shared__ float smem[32 * G4];           // 64 KB
  float* xl = smem;                          // 32x64
  float* hl = smem + 32 * EMBD;              // 32x128
  float* gates = smem;                       // 32x512 (after GEMM)
  const int isbf = *flagp;
  const int tid = threadIdx.x;
  const int n0 = blockIdx.x * 32;

  // ---- stage x_t (fp32) and h_{t-1} into LDS ----
  #pragma unroll
  for (int i = 0; i < 8; ++i) {
    const int idx = tid + i * 256;           // 0..2047
    const int n = idx >> 6, k = idx & 63;
    xl[idx] = ldf(x_user, (size_t)(n0 + n) * (T_STEPS * EMBD) + (size_t)t * EMBD + k, isbf);
  }
  #pragma unroll
  for (int i = 0; i < 16; ++i) {
    const int idx = tid + i * 256;           // 0..4095
    hl[idx] = (t == 0) ? 0.f : h[(size_t)n0 * HD + idx];
  }
  __syncthreads();

  // ---- GEMM: gates[n][col] = sum_k x[n][k] Wih[col][k] + sum_k h[n][k] Whh[col][k]
  const int col0 = tid, col1 = tid + 256;
  float acc0[32], acc1[32];
  #pragma unroll
  for (int n = 0; n < 32; ++n) { acc0[n] = 0.f; acc1[n] = 0.f; }

  for (int k = 0; k < EMBD; ++k) {
    const float w0 = ldf(W_ih, (size_t)col0 * EMBD + k, isbf);
    const float w1 = ldf(W_ih, (size_t)col1 * EMBD + k, isbf);
    #pragma unroll
    for (int n = 0; n < 32; ++n) {
      const float a = xl[n * EMBD + k];
      acc0[n] += a * w0; acc1[n] += a * w1;
    }
  }
  if (t > 0) {
    for (int k = 0; k < HD; ++k) {
      const float w0 = ldf(W_hh, (size_t)col0 * HD + k, isbf);
      const float w1 = ldf(W_hh, (size_t)col1 * HD + k, isbf);
      #pragma unroll
      for (int n = 0; n < 32; ++n) {
        const float a = hl[n * HD + k];
        acc0[n] += a * w0; acc1[n] += a * w1;
      }
    }
  }
  __syncthreads();                           // xl/hl dead; reuse as gates
  #pragma unroll
  for (int n = 0; n < 32; ++n) {
    gates[n * G4 + col0] = acc0[n];
    gates[n * G4 + col1] = acc1[n];
  }
  __syncthreads();

  // ---- LSTM cell: 32 nodes x 128, 16 elems/thread (gate order i,f,g,o) ----
  #pragma unroll
  for (int it = 0; it < 16; ++it) {
    const int lin = it * 256 + tid;
    const int nl = lin >> 7, j = lin & 127;
    const size_t n = (size_t)(n0 + nl);
    const float gi = gates[nl * G4 + j]       + ldf(b_ih, j, isbf)       + ldf(b_hh, j, isbf);
    const float gf = gates[nl * G4 + 128 + j] + ldf(b_ih, 128 + j, isbf) + ldf(b_hh, 128 + j, isbf);
    const float gg = gates[nl * G4 + 256 + j] + ldf(b_ih, 256 + j, isbf) + ldf(b_hh, 256 + j, isbf);
    const float go = gates[nl * G4 + 384 + j] + ldf(b_ih, 384 + j, isbf) + ldf(b_hh, 384 + j, isbf);
    const float iv = sigf(gi), fv = sigf(gf), gv = tanhf(gg), ov = sigf(go);
    const float cold = (t == 0) ? 0.f : cstate[n * HD + j];
    const float cnew = fv * cold + iv * gv;
    cstate[n * HD + j] = cnew;
    h[n * HD + j] = ov * tanhf(cnew);
  }
}

// ---------------- content linear: c = x_content @ Wc^T + bc  (K=64) ----------------
__global__ __launch_bounds__(256) void k_content(
    const void* __restrict__ x_content, const void* __restrict__ Wc,
    const void* __restrict__ bc, float* __restrict__ c_out,
    const int* __restrict__ flagp)
{
  __shared__ float xl[32 * EMBD];
  const int isbf = *flagp;
  const int tid = threadIdx.x;
  const int n0 = blockIdx.x * 32;
  #pragma unroll
  for (int i = 0; i < 8; ++i) {
    const int idx = tid + i * 256;
    xl[idx] = ldf(x_content, (size_t)n0 * EMBD + idx, isbf);
  }
  __syncthreads();
  const int jj = tid & 127, grp = tid >> 7;
  float acc[16];
  #pragma unroll
  for (int nn = 0; nn < 16; ++nn) acc[nn] = 0.f;
  for (int k = 0; k < EMBD; ++k) {
    const float w = ldf(Wc, (size_t)jj * EMBD + k, isbf);
    #pragma unroll
    for (int nn = 0; nn < 16; ++nn)
      acc[nn] += xl[(grp * 16 + nn) * EMBD + k] * w;
  }
  const float bj = ldf(bc, jj, isbf);
  #pragma unroll
  for (int nn = 0; nn < 16; ++nn)
    c_out[(size_t)(n0 + grp * 16 + nn) * HD + jj] = acc[nn] + bj;
}

// ---------------- degree counts ----------------
__global__ void k_count(const int* __restrict__ src, const int* __restrict__ dst,
                        float* __restrict__ cnt_u, float* __restrict__ cnt_c, int E)
{
  const int e = blockIdx.x * blockDim.x + threadIdx.x;
  if (e < E) {
    atomicAdd(cnt_u + (src[e] & NMASK), 1.f);
    atomicAdd(cnt_c + (dst[e] & NMASK), 1.f);
  }
}

// ---------------- scatter-add: agg[sidx[e]][:] += feat[gidx[e]][:] ----------------
__global__ __launch_bounds__(256) void k_scatter(
    const float* __restrict__ feat, const int* __restrict__ gidx,
    const int* __restrict__ sidx, float* __restrict__ agg, int E)
{
  const long long total = (long long)E * HD;
  const long long stride = (long long)gridDim.x * 256;
  for (long long i = (long long)blockIdx.x * 256 + threadIdx.x; i < total; i += stride) {
    const int e = (int)(i >> 7), j = (int)(i & 127);
    const int s = gidx[e] & NMASK, d = sidx[e] & NMASK;
    atomicAdd(agg + (size_t)d * HD + j, feat[(size_t)s * HD + j]);
  }
}

// ---------------- SAGE linear: out = relu(mean @ Wl^T + bl + x @ Wr^T) -------------
__global__ __launch_bounds__(256) void k_sage_lin(
    const float* __restrict__ agg, const float* __restrict__ cnt,
    const float* __restrict__ dstx,
    const void* __restrict__ Wl, const void* __restrict__ bl,
    const void* __restrict__ Wr, float* __restrict__ outp,
    const int* __restrict__ flagp)
{
  __shared__ float ml[32 * HD];
  __shared__ float xl[32 * HD];
  const int isbf = *flagp;
  const int tid = threadIdx.x;
  const int n0 = blockIdx.x * 32;
  #pragma unroll
  for (int i = 0; i < 16; ++i) {
    const int idx = tid + i * 256;
    const int n = idx >> 7;
    const float rc = 1.f / fmaxf(cnt[n0 + n], 1.f);
    ml[idx] = agg[(size_t)n0 * HD + idx] * rc;
    xl[idx] = dstx[(size_t)n0 * HD + idx];
  }
  __syncthreads();
  const int jj = tid & 127, grp = tid >> 7;
  float acc[16];
  #pragma unroll
  for (int nn = 0; nn < 16; ++nn) acc[nn] = 0.f;
  for (int k = 0; k < HD; ++k) {
    const float wl = ldf(Wl, (size_t)jj * HD + k, isbf);
    const float wr = ldf(Wr, (size_t)jj * HD + k, isbf);
    #pragma unroll
    for (int nn = 0; nn < 16; ++nn)
      acc[nn] += ml[(grp * 16 + nn) * HD + k] * wl + xl[(grp * 16 + nn) * HD + k] * wr;
  }
  const float bj = ldf(bl, jj, isbf);
  #pragma unroll
  for (int nn = 0; nn < 16; ++nn)
    outp[(size_t)(n0 + grp * 16 + nn) * HD + jj] = fmaxf(acc[nn] + bj, 0.f);
}

// ---------------- classifier hidden: h1 = relu([u,c] @ W1^T + b1) ----------------
__global__ __launch_bounds__(256) void k_cls(
    const float* __restrict__ u, const float* __restrict__ c,
    const void* __restrict__ W1, const void* __restrict__ b1,
    float* __restrict__ h1, const int* __restrict__ flagp)
{
  __shared__ float ul[32 * HD];
  __shared__ float cl[32 * HD];
  const int isbf = *flagp;
  const int tid = threadIdx.x;
  const int n0 = blockIdx.x * 32;
  #pragma unroll
  for (int i = 0; i < 16; ++i) {
    const int idx = tid + i * 256;
    ul[idx] = u[(size_t)n0 * HD + idx];
    cl[idx] = c[(size_t)n0 * HD + idx];
  }
  __syncthreads();
  const int jj = tid & 127, grp = tid >> 7;
  float acc[16];
  #pragma unroll
  for (int nn = 0; nn < 16; ++nn) acc[nn] = 0.f;
  for (int k = 0; k < HD; ++k) {
    const float wu = ldf(W1, (size_t)jj * 256 + k, isbf);
    const float wc = ldf(W1, (size_t)jj * 256 + 128 + k, isbf);
    #pragma unroll
    for (int nn = 0; nn < 16; ++nn)
      acc[nn] += ul[(grp * 16 + nn) * HD + k] * wu + cl[(grp * 16 + nn) * HD + k] * wc;
  }
  const float bj = ldf(b1, jj, isbf);
  #pragma unroll
  for (int nn = 0; nn < 16; ++nn)
    h1[(size_t)(n0 + grp * 16 + nn) * HD + jj] = fmaxf(acc[nn] + bj, 0.f);
}

// ---------------- output: sigmoid(h1 @ W2^T + b2), one wave per node ----------------
__global__ __launch_bounds__(256) void k_out(
    const float* __restrict__ h1, const void* __restrict__ W2,
    const void* __restrict__ b2, void* __restrict__ out,
    const int* __restrict__ flagp)
{
  const int isbf = *flagp;
  const int wave = threadIdx.x >> 6, lane = threadIdx.x & 63;
  const int n = blockIdx.x * 4 + wave;
  float v = h1[(size_t)n * HD + lane] * ldf(W2, lane, isbf)
          + h1[(size_t)n * HD + 64 + lane] * ldf(W2, 64 + lane, isbf);
  #pragma unroll
  for (int off = 32; off > 0; off >>= 1) v += __shfl_down(v, off, 64);
  if (lane == 0) {
    const float r = sigf(v + ldf(b2, 0, isbf));
    if (isbf) ((bf16*)out)[n] = (bf16)r; else ((float*)out)[n] = r;
  }
}

extern "C" void kernel_launch(void* const* d_in, const int* in_sizes, int n_in,
                              void* d_out, int out_size, void* d_ws, size_t ws_size,
                              hipStream_t stream)
{
  const void* x_user    = d_in[0];
  const void* x_content = d_in[1];
  const int*  edge      = (const int*)d_in[2];
  const void* W_ih      = d_in[3];
  const void* W_hh      = d_in[4];
  const void* b_ih      = d_in[5];
  const void* b_hh      = d_in[6];
  const void* Wc        = d_in[7];
  const void* bc        = d_in[8];
  const void* Wl[2]     = {d_in[9],  d_in[12]};
  const void* blv[2]    = {d_in[10], d_in[13]};
  const void* Wr[2]     = {d_in[11], d_in[14]};
  const void* W1        = d_in[15];
  const void* b1        = d_in[16];
  const void* W2        = d_in[17];
  const void* b2        = d_in[18];

  const int E = in_sizes[2] / 2;
  const int* src = edge;          // edge_index[0]
  const int* dst = edge + E;      // edge_index[1]

  // ---- workspace layout (~80.3 MB), all fp32 internals ----
  const size_t MB = 1u << 20;
  char* ws = (char*)d_ws;
  float* agg  = (float*)ws;                  // 16 MB: LSTM c-state -> agg -> h1
  float* cst  = agg;
  float* h1   = agg;
  float* u0 = (float*)(ws + 16 * MB);        // 16 MB: LSTM h / u ping
  float* c0 = (float*)(ws + 32 * MB);        // 16 MB: c ping
  float* u1 = (float*)(ws + 48 * MB);        // 16 MB: u pong
  float* c1 = (float*)(ws + 64 * MB);        // 16 MB: c pong
  float* cnt_c = (float*)(ws + 80 * MB);     // 128 KB
  float* cnt_u = cnt_c + N_NODES;            // 128 KB
  int*   flag  = (int*)(ws + 80 * MB + 512 * 1024);

  const int AGG4 = (int)(16 * MB / 16);
  const int CNT4 = (int)(2 * N_NODES * sizeof(float) / 16);

  // ---- dtype probe ----
  k_detect<<<1, 64, 0, stream>>>((const unsigned*)x_user, flag);

  // ---- LSTM over 20 steps (sequential) ----
  for (int t = 0; t < T_STEPS; ++t)
    k_lstm_step<<<N_NODES / 32, 256, 0, stream>>>(x_user, W_ih, W_hh, b_ih, b_hh,
                                                  u0, cst, flag, t);
  // ---- content embedding ----
  k_content<<<N_NODES / 32, 256, 0, stream>>>(x_content, Wc, bc, c0, flag);

  // ---- degree counts ----
  k_zero<<<(CNT4 + 255) / 256, 256, 0, stream>>>((float4*)cnt_c, CNT4);
  k_count<<<(E + 255) / 256, 256, 0, stream>>>(src, dst, cnt_u, cnt_c, E);

  // ---- 2 SAGE layers, both directions use OLD u,c ----
  float* ui = u0; float* ci = c0; float* uo = u1; float* co = c1;
  for (int L = 0; L < 2; ++L) {
    k_zero<<<(AGG4 + 255) / 256, 256, 0, stream>>>((float4*)agg, AGG4);
    k_scatter<<<8192, 256, 0, stream>>>(ui, src, dst, agg, E);              // users -> content
    k_sage_lin<<<N_NODES / 32, 256, 0, stream>>>(agg, cnt_c, ci, Wl[L], blv[L], Wr[L], co, flag);
    k_zero<<<(AGG4 + 255) / 256, 256, 0, stream>>>((float4*)agg, AGG4);
    k_scatter<<<8192, 256, 0, stream>>>(ci, dst, src, agg, E);              // content -> users
    k_sage_lin<<<N_NODES / 32, 256, 0, stream>>>(agg, cnt_u, ui, Wl[L], blv[L], Wr[L], uo, flag);
    float* t1 = ui; ui = uo; uo = t1;
    float* t2 = ci; ci = co; co = t2;
  }

  // ---- classifier (h1 overwrites agg region — agg dead by now) ----
  k_cls<<<N_NODES / 32, 256, 0, stream>>>(ui, ci, W1, b1, h1, flag);
  k_out<<<N_NODES / 4, 256, 0, stream>>>(h1, W2, b2, d_out, flag);
}